// Round 2
// baseline (32.389 us; speedup 1.0000x reference)
//
#include <hip/hip_runtime.h>
#include <stdint.h>

#define B_DIM 64
#define L_DIM 4096
#define D_DIM 256
#define TGT 256
#define NG 32                        // row-groups per batch (gather kernel)
#define ROWS_PER_BLOCK (TGT / NG)    // 8

__device__ __forceinline__ int idx_of(int k, float nf) {
    // matches jnp: minimum(round(k/256 * n), n-1) with round-half-even
    float x = rintf((float)k * (1.0f / 256.0f) * nf);
    x = fminf(x, nf - 1.0f);
    return (int)x;
}

// ---------------- Kernel A: per-batch mask compaction -> pos table + n ----
__global__ __launch_bounds__(256)
void build_pos_kernel(const uint8_t* __restrict__ mask_raw,
                      unsigned short* __restrict__ pos_ws,
                      int* __restrict__ n_ws) {
    __shared__ int tsum[256];
    __shared__ int flags[2];
    const int tid = threadIdx.x;
    const int b   = blockIdx.x;

    // mask dtype detection on first 4096 bytes (safe under all layouts)
    if (tid == 0) { flags[0] = 1; flags[1] = 1; }
    __syncthreads();
    {
        const uint32_t* mw = (const uint32_t*)mask_raw;
        bool bad_int = false, bad_f32 = false;
        #pragma unroll
        for (int i = 0; i < 4; ++i) {
            uint32_t w = mw[tid + 256 * i];
            if (w > 1u) bad_int = true;
            if (w != 0u && w != 0x3F800000u) bad_f32 = true;
        }
        if (bad_int) flags[0] = 0;
        if (bad_f32) flags[1] = 0;
    }
    __syncthreads();
    const int flag = flags[0] ? 1 : (flags[1] ? 2 : 0); // 1=int32, 2=f32, 0=byte

    uint32_t bits = 0;
    int cnt = 0;
    {
        const int base = tid * 16;
        if (flag == 1) {
            const int32_t* m = (const int32_t*)mask_raw + (size_t)b * L_DIM;
            #pragma unroll
            for (int i = 0; i < 16; ++i)
                if (m[base + i] != 0) { bits |= (1u << i); ++cnt; }
        } else if (flag == 2) {
            const float* m = (const float*)mask_raw + (size_t)b * L_DIM;
            #pragma unroll
            for (int i = 0; i < 16; ++i)
                if (m[base + i] != 0.0f) { bits |= (1u << i); ++cnt; }
        } else {
            const uint8_t* m = mask_raw + (size_t)b * L_DIM;
            #pragma unroll
            for (int i = 0; i < 16; ++i)
                if (m[base + i] != 0) { bits |= (1u << i); ++cnt; }
        }
    }
    tsum[tid] = cnt;
    __syncthreads();
    for (int off = 1; off < 256; off <<= 1) {
        int v = (tid >= off) ? tsum[tid - off] : 0;
        __syncthreads();
        tsum[tid] += v;
        __syncthreads();
    }
    {
        int p = tsum[tid] - cnt;                 // exclusive prefix
        const int base = tid * 16;
        unsigned short* pos = pos_ws + (size_t)b * L_DIM;
        #pragma unroll
        for (int i = 0; i < 16; ++i)
            if ((bits >> i) & 1u) pos[p++] = (unsigned short)(base + i);
    }
    if (tid == 255) n_ws[b] = tsum[255];
}

// ---------------- Kernel B: pure gather (no LDS, no barriers) -------------
__global__ __launch_bounds__(256)
void gather_kernel(const float* __restrict__ feats,
                   const unsigned short* __restrict__ pos_ws,
                   const int* __restrict__ n_ws,
                   float* __restrict__ out) {
    const int tid  = threadIdx.x;
    const int b    = blockIdx.y;
    const int g    = blockIdx.x;
    const int wv   = tid >> 6;
    const int lane = tid & 63;

    const float nf = (float)n_ws[b];                       // wave-uniform scalar
    const unsigned short* pos = pos_ws + (size_t)b * L_DIM;
    const float* fb = feats + (size_t)b * L_DIM * D_DIM;

    for (int r = wv; r < ROWS_PER_BLOCK; r += 4) {
        const int t  = g * ROWS_PER_BLOCK + r;
        const int s  = idx_of(t, nf);
        const int e  = idx_of(t + 1, nf);
        const int lo = s;
        const int hi = (e > s) ? e : (s + 1);              // s==e -> copy row s
        const float inv = 1.0f / (float)(hi - lo);
        float4 acc = make_float4(0.f, 0.f, 0.f, 0.f);
        for (int i = lo; i < hi; ++i) {
            const int row = pos[i];                        // uniform -> s_load/L1
            const float4 v = *((const float4*)(fb + (size_t)row * D_DIM) + lane);
            acc.x += v.x; acc.y += v.y; acc.z += v.z; acc.w += v.w;
        }
        acc.x *= inv; acc.y *= inv; acc.z *= inv; acc.w *= inv;
        *((float4*)(out + ((size_t)b * TGT + t) * D_DIM) + lane) = acc;
    }
}

// ---------------- Fallback: round-1 single kernel (if ws too small) -------
__global__ __launch_bounds__(256)
void AggregateVideo_fused_kernel(const uint8_t* __restrict__ mask_raw,
                                 const float* __restrict__ feats,
                                 float* __restrict__ out) {
    __shared__ unsigned short pos[L_DIM];
    __shared__ int tsum[256];
    __shared__ int flags[2];

    const int tid = threadIdx.x;
    const int b   = blockIdx.y;
    const int g   = blockIdx.x;

    if (tid == 0) { flags[0] = 1; flags[1] = 1; }
    __syncthreads();
    {
        const uint32_t* mw = (const uint32_t*)mask_raw;
        bool bad_int = false, bad_f32 = false;
        #pragma unroll
        for (int i = 0; i < 4; ++i) {
            uint32_t w = mw[tid + 256 * i];
            if (w > 1u) bad_int = true;
            if (w != 0u && w != 0x3F800000u) bad_f32 = true;
        }
        if (bad_int) flags[0] = 0;
        if (bad_f32) flags[1] = 0;
    }
    __syncthreads();
    const int flag = flags[0] ? 1 : (flags[1] ? 2 : 0);

    uint32_t bits = 0;
    int cnt = 0;
    {
        const int base = tid * 16;
        if (flag == 1) {
            const int32_t* m = (const int32_t*)mask_raw + (size_t)b * L_DIM;
            #pragma unroll
            for (int i = 0; i < 16; ++i)
                if (m[base + i] != 0) { bits |= (1u << i); ++cnt; }
        } else if (flag == 2) {
            const float* m = (const float*)mask_raw + (size_t)b * L_DIM;
            #pragma unroll
            for (int i = 0; i < 16; ++i)
                if (m[base + i] != 0.0f) { bits |= (1u << i); ++cnt; }
        } else {
            const uint8_t* m = mask_raw + (size_t)b * L_DIM;
            #pragma unroll
            for (int i = 0; i < 16; ++i)
                if (m[base + i] != 0) { bits |= (1u << i); ++cnt; }
        }
    }
    tsum[tid] = cnt;
    __syncthreads();
    for (int off = 1; off < 256; off <<= 1) {
        int v = (tid >= off) ? tsum[tid - off] : 0;
        __syncthreads();
        tsum[tid] += v;
        __syncthreads();
    }
    const int n = tsum[255];
    {
        int p = tsum[tid] - cnt;
        const int base = tid * 16;
        #pragma unroll
        for (int i = 0; i < 16; ++i)
            if ((bits >> i) & 1u) pos[p++] = (unsigned short)(base + i);
    }
    __syncthreads();

    const float nf = (float)n;
    const int wv   = tid >> 6;
    const int lane = tid & 63;
    for (int r = wv; r < ROWS_PER_BLOCK; r += 4) {
        const int t = g * ROWS_PER_BLOCK + r;
        const int s = idx_of(t, nf);
        const int e = idx_of(t + 1, nf);
        const int lo = s;
        const int hi = (e > s) ? e : (s + 1);
        const float inv = 1.0f / (float)(hi - lo);
        float4 acc = make_float4(0.f, 0.f, 0.f, 0.f);
        for (int i = lo; i < hi; ++i) {
            const int row = pos[i];
            const float4 v =
                *((const float4*)(feats + ((size_t)b * L_DIM + row) * D_DIM) + lane);
            acc.x += v.x; acc.y += v.y; acc.z += v.z; acc.w += v.w;
        }
        acc.x *= inv; acc.y *= inv; acc.z *= inv; acc.w *= inv;
        *((float4*)(out + ((size_t)b * TGT + t) * D_DIM) + lane) = acc;
    }
}

extern "C" void kernel_launch(void* const* d_in, const int* in_sizes, int n_in,
                              void* d_out, int out_size, void* d_ws, size_t ws_size,
                              hipStream_t stream) {
    const float*   feats = (const float*)d_in[0];
    const uint8_t* masks = (const uint8_t*)d_in[1];
    float*         out   = (float*)d_out;
    (void)in_sizes; (void)n_in; (void)out_size;

    const size_t pos_bytes = (size_t)B_DIM * L_DIM * sizeof(unsigned short); // 512 KiB
    const size_t need      = pos_bytes + B_DIM * sizeof(int);

    if (ws_size >= need) {
        unsigned short* pos_ws = (unsigned short*)d_ws;
        int*            n_ws   = (int*)((uint8_t*)d_ws + pos_bytes);
        build_pos_kernel<<<B_DIM, 256, 0, stream>>>(masks, pos_ws, n_ws);
        dim3 grid(NG, B_DIM);
        gather_kernel<<<grid, 256, 0, stream>>>(feats, pos_ws, n_ws, out);
    } else {
        dim3 grid(NG, B_DIM);
        AggregateVideo_fused_kernel<<<grid, 256, 0, stream>>>(masks, feats, out);
    }
}

// Round 3
// 31.707 us; speedup vs baseline: 1.0215x; 1.0215x over previous
//
#include <hip/hip_runtime.h>
#include <stdint.h>

#define B_DIM 64
#define L_DIM 4096
#define D_DIM 256
#define TGT 256
#define BLK 512                      // threads per block (8 waves)
#define ROWS_PER_BLOCK 16
#define NG (TGT / ROWS_PER_BLOCK)    // 16 groups per batch

__device__ __forceinline__ int idx_of(int k, float nf) {
    // matches jnp: minimum(round(k/256 * n), n-1) with round-half-even
    float x = rintf((float)k * (1.0f / 256.0f) * nf);
    x = fminf(x, nf - 1.0f);
    return (int)x;
}

__global__ __launch_bounds__(BLK)
void AggregateVideo_kernel(const uint8_t* __restrict__ mask_raw,
                           const float* __restrict__ feats,
                           float* __restrict__ out) {
    __shared__ unsigned short pos[L_DIM];          // compact idx -> original row
    __shared__ unsigned long long words[L_DIM / 64];
    __shared__ int pref[L_DIM / 64];
    __shared__ int flags[2];
    __shared__ int nsh;

    const int tid  = threadIdx.x;
    const int b    = blockIdx.y;
    const int g    = blockIdx.x;
    const int wv   = tid >> 6;
    const int lane = tid & 63;

    // ---- mask dtype detection on first 4096 bytes (valid under all layouts)
    if (tid == 0) { flags[0] = 1; flags[1] = 1; }
    __syncthreads();
    {
        const uint32_t* mw = (const uint32_t*)mask_raw;
        bool bad_int = false, bad_f32 = false;
        #pragma unroll
        for (int i = 0; i < 2; ++i) {
            uint32_t w = mw[tid + BLK * i];
            if (w > 1u) bad_int = true;
            if (w != 0u && w != 0x3F800000u) bad_f32 = true;
        }
        if (bad_int) flags[0] = 0;
        if (bad_f32) flags[1] = 0;
    }
    __syncthreads();
    const int flag = flags[0] ? 1 : (flags[1] ? 2 : 0); // 1=int32, 2=f32, 0=byte

    // ---- ballot-compaction: coalesced mask loads -> 64 bitmask words
    {
        if (flag == 1) {
            const int32_t* m = (const int32_t*)mask_raw + (size_t)b * L_DIM;
            #pragma unroll
            for (int i = 0; i < L_DIM / BLK; ++i) {
                const int j = i * BLK + tid;                 // j = i*BLK + wv*64 + lane
                unsigned long long bal = __ballot(m[j] != 0);
                if (lane == 0) words[j >> 6] = bal;
            }
        } else if (flag == 2) {
            const float* m = (const float*)mask_raw + (size_t)b * L_DIM;
            #pragma unroll
            for (int i = 0; i < L_DIM / BLK; ++i) {
                const int j = i * BLK + tid;
                unsigned long long bal = __ballot(m[j] != 0.0f);
                if (lane == 0) words[j >> 6] = bal;
            }
        } else {
            const uint8_t* m = mask_raw + (size_t)b * L_DIM;
            #pragma unroll
            for (int i = 0; i < L_DIM / BLK; ++i) {
                const int j = i * BLK + tid;
                unsigned long long bal = __ballot(m[j] != 0);
                if (lane == 0) words[j >> 6] = bal;
            }
        }
    }
    __syncthreads();

    // ---- wave 0: popcount + inclusive shfl-scan over the 64 words
    if (tid < 64) {
        const unsigned long long wd = words[tid];
        const int c = __popcll(wd);
        int inc = c;
        #pragma unroll
        for (int off = 1; off < 64; off <<= 1) {
            int v = __shfl_up(inc, off);
            if (tid >= off) inc += v;
        }
        pref[tid] = inc - c;            // exclusive prefix
        if (tid == 63) nsh = inc;       // n
    }
    __syncthreads();

    // ---- expand bitmask words to pos[] (each thread: one byte of one word)
    {
        const int w      = tid >> 3;
        const int startb = (tid & 7) * 8;
        const unsigned long long wd = words[w];
        const unsigned long long below =
            startb ? (wd & ((1ull << startb) - 1ull)) : 0ull;
        int p = pref[w] + __popcll(below);
        const int base = w * 64 + startb;
        unsigned int byte = (unsigned int)((wd >> startb) & 0xFFull);
        while (byte) {
            const int bit = __ffs(byte) - 1;
            pos[p++] = (unsigned short)(base + bit);
            byte &= byte - 1;
        }
    }
    __syncthreads();

    const float nf = (float)nsh;
    const float* fb = feats + (size_t)b * L_DIM * D_DIM;

    // ---- gather: each wave owns 2 output rows
    #pragma unroll
    for (int rr = 0; rr < 2; ++rr) {
        const int t  = g * ROWS_PER_BLOCK + wv + rr * 8;
        const int s  = idx_of(t, nf);
        const int e  = idx_of(t + 1, nf);
        const int lo = s;
        const int hi = (e > s) ? e : (s + 1);      // s==e -> copy row s
        const int cnt = hi - lo;                   // <= 17
        const float inv = 1.0f / (float)cnt;

        // lane-parallel fetch of all row indices for this bucket (one LDS read)
        const int myrow = (lane < cnt) ? (int)pos[lo + lane] : 0;

        float4 a0 = make_float4(0.f, 0.f, 0.f, 0.f);
        float4 a1 = make_float4(0.f, 0.f, 0.f, 0.f);
        float4 a2 = make_float4(0.f, 0.f, 0.f, 0.f);
        float4 a3 = make_float4(0.f, 0.f, 0.f, 0.f);
        int k = 0;
        for (; k + 4 <= cnt; k += 4) {
            const int r0 = __shfl(myrow, k);
            const int r1 = __shfl(myrow, k + 1);
            const int r2 = __shfl(myrow, k + 2);
            const int r3 = __shfl(myrow, k + 3);
            const float4 v0 = *((const float4*)(fb + (size_t)r0 * D_DIM) + lane);
            const float4 v1 = *((const float4*)(fb + (size_t)r1 * D_DIM) + lane);
            const float4 v2 = *((const float4*)(fb + (size_t)r2 * D_DIM) + lane);
            const float4 v3 = *((const float4*)(fb + (size_t)r3 * D_DIM) + lane);
            a0.x += v0.x; a0.y += v0.y; a0.z += v0.z; a0.w += v0.w;
            a1.x += v1.x; a1.y += v1.y; a1.z += v1.z; a1.w += v1.w;
            a2.x += v2.x; a2.y += v2.y; a2.z += v2.z; a2.w += v2.w;
            a3.x += v3.x; a3.y += v3.y; a3.z += v3.z; a3.w += v3.w;
        }
        for (; k < cnt; ++k) {
            const int r0 = __shfl(myrow, k);
            const float4 v0 = *((const float4*)(fb + (size_t)r0 * D_DIM) + lane);
            a0.x += v0.x; a0.y += v0.y; a0.z += v0.z; a0.w += v0.w;
        }
        a0.x += a1.x; a0.y += a1.y; a0.z += a1.z; a0.w += a1.w;
        a2.x += a3.x; a2.y += a3.y; a2.z += a3.z; a2.w += a3.w;
        a0.x += a2.x; a0.y += a2.y; a0.z += a2.z; a0.w += a2.w;
        a0.x *= inv; a0.y *= inv; a0.z *= inv; a0.w *= inv;
        *((float4*)(out + ((size_t)b * TGT + t) * D_DIM) + lane) = a0;
    }
}

extern "C" void kernel_launch(void* const* d_in, const int* in_sizes, int n_in,
                              void* d_out, int out_size, void* d_ws, size_t ws_size,
                              hipStream_t stream) {
    const float*   feats = (const float*)d_in[0];
    const uint8_t* masks = (const uint8_t*)d_in[1];
    float*         out   = (float*)d_out;
    (void)in_sizes; (void)n_in; (void)out_size; (void)d_ws; (void)ws_size;

    dim3 grid(NG, B_DIM);
    AggregateVideo_kernel<<<grid, BLK, 0, stream>>>(masks, feats, out);
}